// Round 1
// baseline (641.425 us; speedup 1.0000x reference)
//
#include <hip/hip_runtime.h>

// Fused LSTM (B=4096,T=365,F=32,H=50,relu cell act) + dense head.
// 256 blocks x 512 thr; block owns 16 batch rows for all 365 steps.
// Per step: g[16x200] = [x_t | h | 1](f16 LDS) x W(f16 B-frags, persistent VGPRs)
// via v_mfma_f32_16x16x16_f16 (6 k-steps, 13 N-tiles / 8 waves); gates f32 VALU;
// h -> f16 LDS. Weights read once; x read once from HBM (191 MB).

typedef _Float16 f16;
typedef f16 f16x4 __attribute__((ext_vector_type(4)));
typedef float f32x4 __attribute__((ext_vector_type(4)));

#define T_STEPS 365
#define F_IN    32
#define H_U     50
#define NG      200   // 4H
#define ASTR    100   // A row stride in halves (gcd trick: 100*2B -> bank-spread)
#define GSTR    20    // G col stride in floats (pad vs 16 to break conflicts)

__global__ __launch_bounds__(512)
void lstm_fused(const float* __restrict__ x,
                const float* __restrict__ wk,
                const float* __restrict__ wr,
                const float* __restrict__ bias,
                const float* __restrict__ dw,
                const float* __restrict__ db,
                float* __restrict__ out)
{
    __shared__ f16   As[16 * ASTR];    // [row][k]: k 0..31 = x_t, 32..81 = h, 82 = 1.0 (bias), 83..95 = 0
    __shared__ float Gs[208 * GSTR];   // [col][row] gate pre-activations (f32)

    const int tid  = threadIdx.x;
    const int lane = tid & 63;
    const int wave = tid >> 6;          // 0..7
    const int cl   = lane & 15;         // MFMA: A-row / B-col / D-col
    const int lg   = lane >> 4;         // MFMA lane group (k = 4*lg+e; D rows 4*lg..4*lg+3)
    const long row0 = (long)blockIdx.x * 16;

    // ---- persistent weight fragments: tile0 = wave, tile1 = 8+wave (waves 0..4) ----
    f16x4 bf0[6], bf1[6];
    {
        const int c0i = wave * 16 + cl;         // < 128, always valid
        const int c1i = (8 + wave) * 16 + cl;   // up to 255, guard vs NG
        #pragma unroll
        for (int ks = 0; ks < 6; ++ks) {
            f16x4 v0, v1;
            #pragma unroll
            for (int e = 0; e < 4; ++e) {
                const int k = ks * 16 + lg * 4 + e;
                float w0 = 0.f, w1 = 0.f;
                if (k < 32) {
                    w0 = wk[k * NG + c0i];
                    if (c1i < NG) w1 = wk[k * NG + c1i];
                } else if (k < 82) {
                    w0 = wr[(k - 32) * NG + c0i];
                    if (c1i < NG) w1 = wr[(k - 32) * NG + c1i];
                } else if (k == 82) {
                    w0 = bias[c0i];
                    if (c1i < NG) w1 = bias[c1i];
                }
                v0[e] = (f16)w0;
                v1[e] = (f16)w1;
            }
            bf0[ks] = v0;
            bf1[ks] = v1;
        }
    }

    // ---- init LDS: zero A (covers h0=0 and k-pad), then bias-one slot + x(0) ----
    for (int i = tid; i < 16 * ASTR / 2; i += 512) ((unsigned*)As)[i] = 0u;
    __syncthreads();
    if (tid < 16) As[tid * ASTR + 82] = (f16)1.0f;
    if (tid < 256) {
        const int r = tid >> 4, f = (tid & 15) * 2;
        const float2 v = *(const float2*)(x + ((row0 + r) * T_STEPS + 0) * F_IN + f);
        union { f16 h[2]; unsigned u; } pk;
        pk.h[0] = (f16)v.x; pk.h[1] = (f16)v.y;
        *(unsigned*)&As[r * ASTR + f] = pk.u;
    }
    __syncthreads();

    float c0 = 0.f, c1 = 0.f;                 // cell state, static (row,unit) ownership
    const bool has_t1 = (wave < 5);
    const bool has_p1 = (tid < 288);          // (tid+512) < 800
    const int r_up = tid & 15;
    const int u_p0 = tid >> 4;                // units 0..31
    const int u_p1 = u_p0 + 32;               // units 32..49

    for (int t = 0; t < T_STEPS; ++t) {
        // --- MFMA phase: A-frags from LDS, accumulate g, write to Gs ---
        const f16* ap = &As[cl * ASTR + lg * 4];
        const f16x4 a0 = *(const f16x4*)(ap +  0);
        const f16x4 a1 = *(const f16x4*)(ap + 16);
        const f16x4 a2 = *(const f16x4*)(ap + 32);
        const f16x4 a3 = *(const f16x4*)(ap + 48);
        const f16x4 a4 = *(const f16x4*)(ap + 64);
        const f16x4 a5 = *(const f16x4*)(ap + 80);

        f32x4 acc = {0.f, 0.f, 0.f, 0.f};
        acc = __builtin_amdgcn_mfma_f32_16x16x16f16(a0, bf0[0], acc, 0, 0, 0);
        acc = __builtin_amdgcn_mfma_f32_16x16x16f16(a1, bf0[1], acc, 0, 0, 0);
        acc = __builtin_amdgcn_mfma_f32_16x16x16f16(a2, bf0[2], acc, 0, 0, 0);
        acc = __builtin_amdgcn_mfma_f32_16x16x16f16(a3, bf0[3], acc, 0, 0, 0);
        acc = __builtin_amdgcn_mfma_f32_16x16x16f16(a4, bf0[4], acc, 0, 0, 0);
        acc = __builtin_amdgcn_mfma_f32_16x16x16f16(a5, bf0[5], acc, 0, 0, 0);
        *(f32x4*)&Gs[(wave * 16 + cl) * GSTR + lg * 4] = acc;
        if (has_t1) {
            f32x4 acc1 = {0.f, 0.f, 0.f, 0.f};
            acc1 = __builtin_amdgcn_mfma_f32_16x16x16f16(a0, bf1[0], acc1, 0, 0, 0);
            acc1 = __builtin_amdgcn_mfma_f32_16x16x16f16(a1, bf1[1], acc1, 0, 0, 0);
            acc1 = __builtin_amdgcn_mfma_f32_16x16x16f16(a2, bf1[2], acc1, 0, 0, 0);
            acc1 = __builtin_amdgcn_mfma_f32_16x16x16f16(a3, bf1[3], acc1, 0, 0, 0);
            acc1 = __builtin_amdgcn_mfma_f32_16x16x16f16(a4, bf1[4], acc1, 0, 0, 0);
            acc1 = __builtin_amdgcn_mfma_f32_16x16x16f16(a5, bf1[5], acc1, 0, 0, 0);
            *(f32x4*)&Gs[((8 + wave) * 16 + cl) * GSTR + lg * 4] = acc1;
        }
        __syncthreads();

        // --- gate/update phase: each thread owns (row, unit) pairs; c in regs ---
        {
            const float gi = Gs[u_p0 * GSTR + r_up];
            const float gf = Gs[(50 + u_p0) * GSTR + r_up];
            const float gc = Gs[(100 + u_p0) * GSTR + r_up];
            const float go = Gs[(150 + u_p0) * GSTR + r_up];
            const float ig = 1.f / (1.f + __expf(-gi));
            const float fg = 1.f / (1.f + __expf(-gf));
            const float cd = fmaxf(gc, 0.f);
            const float og = 1.f / (1.f + __expf(-go));
            c0 = fg * c0 + ig * cd;
            const float hv = og * fmaxf(c0, 0.f);
            As[r_up * ASTR + 32 + u_p0] = (f16)hv;
            if (t == T_STEPS - 1) Gs[u_p0 * GSTR + r_up] = hv;  // own i-gate slot: race-free
        }
        if (has_p1) {
            const float gi = Gs[u_p1 * GSTR + r_up];
            const float gf = Gs[(50 + u_p1) * GSTR + r_up];
            const float gc = Gs[(100 + u_p1) * GSTR + r_up];
            const float go = Gs[(150 + u_p1) * GSTR + r_up];
            const float ig = 1.f / (1.f + __expf(-gi));
            const float fg = 1.f / (1.f + __expf(-gf));
            const float cd = fmaxf(gc, 0.f);
            const float og = 1.f / (1.f + __expf(-go));
            c1 = fg * c1 + ig * cd;
            const float hv = og * fmaxf(c1, 0.f);
            As[r_up * ASTR + 32 + u_p1] = (f16)hv;
            if (t == T_STEPS - 1) Gs[u_p1 * GSTR + r_up] = hv;
        }
        // stage x(t+1) (disjoint LDS region from h writes / Gs reads)
        if (t + 1 < T_STEPS && tid < 256) {
            const int r = tid >> 4, f = (tid & 15) * 2;
            const float2 v = *(const float2*)(x + ((row0 + r) * T_STEPS + (t + 1)) * F_IN + f);
            union { f16 h[2]; unsigned u; } pk;
            pk.h[0] = (f16)v.x; pk.h[1] = (f16)v.y;
            *(unsigned*)&As[r * ASTR + f] = pk.u;
        }
        __syncthreads();
    }

    // --- dense head: out[row] = h_last . dense_w + dense_b (h_last f32 in Gs) ---
    if (tid < 16) {
        float acc = db[0];
        #pragma unroll
        for (int u = 0; u < H_U; ++u) acc += Gs[u * GSTR + tid] * dw[u];
        out[row0 + tid] = acc;
    }
}

extern "C" void kernel_launch(void* const* d_in, const int* in_sizes, int n_in,
                              void* d_out, int out_size, void* d_ws, size_t ws_size,
                              hipStream_t stream) {
    (void)in_sizes; (void)n_in; (void)d_ws; (void)ws_size; (void)out_size;
    const float* x  = (const float*)d_in[0];
    const float* wk = (const float*)d_in[1];
    const float* wr = (const float*)d_in[2];
    const float* bs = (const float*)d_in[3];
    const float* dw = (const float*)d_in[4];
    const float* db = (const float*)d_in[5];
    float* out = (float*)d_out;
    hipLaunchKernelGGL(lstm_fused, dim3(4096 / 16), dim3(512), 0, stream,
                       x, wk, wr, bs, dw, db, out);
}

// Round 2
// 455.244 us; speedup vs baseline: 1.4090x; 1.4090x over previous
//
#include <hip/hip_runtime.h>

// Fused LSTM (B=4096,T=365,F=32,H=50,relu cell) + dense head. v2.
// 256 blocks x 256 thr (4 waves); block owns 16 batch rows, 365 serial steps.
// Key structure vs v1:
//  - x loaded global->registers in MFMA A-fragment layout, prefetched 2 steps
//    ahead (manual A/B reg double-buffer) -> no VM latency on the step chain.
//  - Weight columns gate-permuted (unit u gates i,f,c,o at cols 4u..4u+3) so
//    each 16-col MFMA tile holds complete units -> gate phase is wave-local
//    (Gs write+read same wave, no barrier) -> ONE barrier per step.
//  - h ping-pong LDS buffer (read As[p], write As[p^1]) enables the single
//    barrier. Bias folded in as A-row k'=50 (value 1.0).
//  - sigmoid via __expf + v_rcp (no exact-div sequence).

typedef _Float16 f16;
typedef f16 f16x4 __attribute__((ext_vector_type(4)));
typedef float f32x4 __attribute__((ext_vector_type(4)));

#define T_STEPS 365
#define F_IN    32
#define H_U     50
#define NG      200
#define AST     72    // halves per As row: 8B-aligned rows, 2-way max on b64 reads
#define GST     212   // floats per Gs row: 16B-aligned b128 gate reads, ~2-way

__global__ __launch_bounds__(256)
void lstm_fused(const float* __restrict__ x,
                const float* __restrict__ wk,
                const float* __restrict__ wr,
                const float* __restrict__ bias,
                const float* __restrict__ dw,
                const float* __restrict__ db,
                float* __restrict__ out)
{
    __shared__ f16   As[2][16 * AST];   // [buf][row][k']: k'=0..49 h, 50 = 1.0 (bias), 51..63 = 0
    __shared__ float Gs[16 * GST];      // [row][col'] gate pre-activations, wave-private cols

    const int tid  = threadIdx.x;
    const int lane = tid & 63;
    const int w    = tid >> 6;          // wave 0..3
    const int cl   = lane & 15;         // A-row / B-col-in-tile / D-col
    const int lg   = lane >> 4;         // lane group: A k = 4*lg+e; D rows 4*lg..4*lg+3
    const long row0 = (long)blockIdx.x * 16;

    // tiles of this wave: {w, w+4, w+8} and tile 12 for wave 3
    int nj[4]; nj[0] = w; nj[1] = w + 4; nj[2] = w + 8; nj[3] = 12;

    // ---- persistent gate-permuted B fragments ----
    // new col c' = 16n+cl -> unit u = 4n + (cl>>2), gate g = cl&3
    // orig col = g*50 + u  (keras order [i,f,c,o] blocks of H)
    f16x4 bf[4][6];
    #pragma unroll
    for (int j = 0; j < 4; ++j) {
        const int n = nj[j];
        const int u = 4 * n + (cl >> 2);
        const int g = cl & 3;
        const int corig = g * H_U + u;
        const bool cv = (u < H_U) && (j != 3 || w == 3);
        #pragma unroll
        for (int ks = 0; ks < 6; ++ks) {
            f16x4 v;
            #pragma unroll
            for (int e = 0; e < 4; ++e) {
                const int k = ks * 16 + lg * 4 + e;
                float wv = 0.f;
                if (cv) {
                    if (k < 32)      wv = wk[k * NG + corig];
                    else if (k < 82) wv = wr[(k - 32) * NG + corig];
                    else if (k == 82) wv = bias[corig];
                }
                v[e] = (f16)wv;
            }
            bf[j][ks] = v;
        }
    }

    // ---- init LDS ----
    for (int i = tid; i < 16 * AST; i += 256) { As[0][i] = (f16)0.f; As[1][i] = (f16)0.f; }
    __syncthreads();
    if (tid < 16) { As[0][tid * AST + 50] = (f16)1.f; As[1][tid * AST + 50] = (f16)1.f; }
    __syncthreads();

    // ---- x prefetch pipeline (depth 2, manual A/B regs) ----
    const float* xrow = x + (row0 + cl) * (long)(T_STEPS * F_IN);
    float4 xlA = *(const float4*)(xrow + 0 * F_IN + 4 * lg);
    float4 xhA = *(const float4*)(xrow + 0 * F_IN + 4 * lg + 16);
    float4 xlB = *(const float4*)(xrow + 1 * F_IN + 4 * lg);
    float4 xhB = *(const float4*)(xrow + 1 * F_IN + 4 * lg + 16);

    float c0 = 0.f, c1 = 0.f, c2 = 0.f, c3 = 0.f;

    auto step = [&](int t, float4& xl, float4& xh) {
        const int p = t & 1;
        // A fragments: x part from regs, h part from LDS
        f16x4 a0, a1, ah[4];
        a0[0] = (f16)xl.x; a0[1] = (f16)xl.y; a0[2] = (f16)xl.z; a0[3] = (f16)xl.w;
        a1[0] = (f16)xh.x; a1[1] = (f16)xh.y; a1[2] = (f16)xh.z; a1[3] = (f16)xh.w;
        #pragma unroll
        for (int jp = 0; jp < 4; ++jp)
            ah[jp] = *(const f16x4*)&As[p][cl * AST + 16 * jp + 4 * lg];
        // prefetch x(t+2) into the same regs (WAR after cvt; lands next use)
        if (t + 2 < T_STEPS) {
            xl = *(const float4*)(xrow + (t + 2) * F_IN + 4 * lg);
            xh = *(const float4*)(xrow + (t + 2) * F_IN + 4 * lg + 16);
        }
        // MFMA per owned tile, scatter acc to wave-private Gs cols
        #pragma unroll
        for (int j = 0; j < 4; ++j) {
            if (j != 3 || w == 3) {
                const int n = nj[j];
                f32x4 acc = {0.f, 0.f, 0.f, 0.f};
                acc = __builtin_amdgcn_mfma_f32_16x16x16f16(a0,    bf[j][0], acc, 0, 0, 0);
                acc = __builtin_amdgcn_mfma_f32_16x16x16f16(a1,    bf[j][1], acc, 0, 0, 0);
                acc = __builtin_amdgcn_mfma_f32_16x16x16f16(ah[0], bf[j][2], acc, 0, 0, 0);
                acc = __builtin_amdgcn_mfma_f32_16x16x16f16(ah[1], bf[j][3], acc, 0, 0, 0);
                acc = __builtin_amdgcn_mfma_f32_16x16x16f16(ah[2], bf[j][4], acc, 0, 0, 0);
                acc = __builtin_amdgcn_mfma_f32_16x16x16f16(ah[3], bf[j][5], acc, 0, 0, 0);
                #pragma unroll
                for (int e = 0; e < 4; ++e)
                    Gs[(4 * lg + e) * GST + 16 * n + cl] = acc[e];
            }
        }
        // gates: wave-local. lane owns (row=cl, unit=4*n(j)+lg)
        #pragma unroll
        for (int j = 0; j < 4; ++j) {
            const bool valid = (j != 3) || (w == 3 && lg < 2);
            if (valid) {
                const int n = nj[j];
                const int u = 4 * n + lg;
                const f32x4 g4 = *(const f32x4*)&Gs[cl * GST + 16 * n + 4 * lg];
                const float ig = __builtin_amdgcn_rcpf(1.f + __expf(-g4[0]));
                const float fg = __builtin_amdgcn_rcpf(1.f + __expf(-g4[1]));
                const float cd = fmaxf(g4[2], 0.f);
                const float og = __builtin_amdgcn_rcpf(1.f + __expf(-g4[3]));
                float& c = (j == 0) ? c0 : ((j == 1) ? c1 : ((j == 2) ? c2 : c3));
                c = fg * c + ig * cd;
                const float hv = og * fmaxf(c, 0.f);
                As[p ^ 1][cl * AST + u] = (f16)hv;
            }
        }
        __syncthreads();
    };

    for (int m = 0; m < (T_STEPS - 1) / 2; ++m) {
        step(2 * m,     xlA, xhA);
        step(2 * m + 1, xlB, xhB);
    }
    step(T_STEPS - 1, xlA, xhA);   // t=364 (even, uses A regs; prefetch skipped)

    // ---- dense head: h_last is in As[1] (last step wrote p^1 = 1) ----
    if (tid < 16) {
        float acc = db[0];
        #pragma unroll
        for (int u = 0; u < H_U; ++u)
            acc += (float)As[1][tid * AST + u] * dw[u];
        out[row0 + tid] = acc;
    }
}

extern "C" void kernel_launch(void* const* d_in, const int* in_sizes, int n_in,
                              void* d_out, int out_size, void* d_ws, size_t ws_size,
                              hipStream_t stream) {
    (void)in_sizes; (void)n_in; (void)d_ws; (void)ws_size; (void)out_size;
    const float* x  = (const float*)d_in[0];
    const float* wk = (const float*)d_in[1];
    const float* wr = (const float*)d_in[2];
    const float* bs = (const float*)d_in[3];
    const float* dw = (const float*)d_in[4];
    const float* db = (const float*)d_in[5];
    float* out = (float*)d_out;
    hipLaunchKernelGGL(lstm_fused, dim3(4096 / 16), dim3(256), 0, stream,
                       x, wk, wr, bs, dw, db, out);
}